// Round 20
// baseline (273.029 us; speedup 1.0000x reference)
//
#include <hip/hip_runtime.h>
#include <stdint.h>

#define NN 1327104
#define NQ 331776
#define NB 1296
#define PRE_NMS_ 6000
#define POST_NMS_ 300
#define LB_CAP 16384
#define NPAD 6144
#define NWORD 96
#define KB 16
#define MATB 192
#define NREP 8

// ---------- helpers ----------

static __device__ __forceinline__ uint32_t score_key(float s) {
  uint32_t b = __float_as_uint(s);
  uint32_t u = b ^ (((int32_t)b < 0) ? 0xFFFFFFFFu : 0x80000000u);
  return ~u;                     // ascending key == descending score
}

static __device__ __forceinline__ uint32_t f2s(float v) {
  uint32_t b = __float_as_uint(v);
  return b ^ (((int32_t)b < 0) ? 0xFFFFFFFFu : 0x80000000u);
}

// Exact replication of reference box decode + _clip_boxes + keep mask.
static __device__ __forceinline__ void compute_box(float4 an, float4 de,
    float& x1, float& y1, float& wc, float& hc, bool& keep) {
  float bx = fmaxf(an.x + de.x, 0.0f);
  float by = fmaxf(an.y + de.y, 0.0f);
  float bw = fmaxf(an.z + de.z, 0.0f);
  float bh = fmaxf(an.w + de.w, 0.0f);
  float x2 = bx + bw - 1.0f;
  float y2 = by + bh - 1.0f;
  x1 = fminf(bx, 383.0f);
  y1 = fminf(by, 383.0f);
  x2 = fminf(x2, 383.0f);
  y2 = fminf(y2, 383.0f);
  wc = x2 - x1 + 1.0f;
  hc = y2 - y1 + 1.0f;
  keep = (wc >= 2.0f) && (hc >= 2.0f);
}

// uniform 18-bit fixed-point bucket (x 2^18 exact for floats -> monotone)
static __device__ __forceinline__ uint32_t kb18_of(float s) {
  return (uint32_t)(s * 262144.0f);
}

static __device__ __forceinline__ uint32_t wscan(uint32_t v, int l) {
  #pragma unroll
  for (int off = 1; off < 64; off <<= 1) {
    uint32_t u = __shfl_up(v, off);
    if (l >= off) v += u;
  }
  return v;
}

// pick level 1 over replicated hist1r[NREP][320] (257 used): (selR8, base1)
static __device__ __forceinline__ void pick1_f(const uint32_t* __restrict__ h1r,
                                               uint32_t& selR8, uint32_t& base1) {
  int l = threadIdx.x & 63;
  uint32_t a0 = 0, a1 = 0, a2 = 0, a3 = 0, a4 = 0;
  #pragma unroll
  for (int r = 0; r < NREP; ++r) {
    const uint32_t* h1 = h1r + r * 320;
    a0 += h1[l*5]; a1 += h1[l*5+1]; a2 += h1[l*5+2]; a3 += h1[l*5+3]; a4 += h1[l*5+4];
  }
  uint32_t c0 = a0, c1 = c0+a1, c2 = c1+a2, c3 = c2+a3, c4 = c3+a4;
  uint32_t inc = wscan(c4, l);
  uint32_t excl = inc - c4;
  bool hit = (excl < PRE_NMS_) && (inc >= PRE_NMS_);
  unsigned long long hb = __ballot(hit);
  int hl = __ffsll(hb) - 1;
  uint32_t k, cb;
  if      (excl + c0 >= PRE_NMS_) { k = 0; cb = 0;  }
  else if (excl + c1 >= PRE_NMS_) { k = 1; cb = c0; }
  else if (excl + c2 >= PRE_NMS_) { k = 2; cb = c1; }
  else if (excl + c3 >= PRE_NMS_) { k = 3; cb = c2; }
  else                            { k = 4; cb = c3; }
  selR8 = __shfl(l*5u + k, hl);
  base1 = __shfl(excl + cb, hl);
}

// pick over LDS hist[1024] with target T>=1: (sel10, base)
static __device__ __forceinline__ void pickT_lds(const uint32_t* __restrict__ h2,
                                                 uint32_t T,
                                                 uint32_t& sel10, uint32_t& base) {
  int l = threadIdx.x & 63;
  uint32_t h[16];
  #pragma unroll
  for (int k = 0; k < 16; ++k) h[k] = h2[l*16 + k];
  uint32_t cum[16]; cum[0] = h[0];
  #pragma unroll
  for (int k = 1; k < 16; ++k) cum[k] = cum[k-1] + h[k];
  uint32_t inc = wscan(cum[15], l);
  uint32_t excl = inc - cum[15];
  bool hit = (excl < T) && (inc >= T);
  unsigned long long hb = __ballot(hit);
  int hl = __ffsll(hb) - 1;
  uint32_t k = 15, cb = cum[14];
  #pragma unroll
  for (int kk = 15; kk >= 0; --kk)
    if (excl + cum[kk] >= T) { k = (uint32_t)kk; cb = kk ? cum[kk-1] : 0u; }
  sel10 = __shfl(l*16u + k, hl);
  base  = __shfl(excl + cb, hl);
}

// decode + write one selection entry (NMS key + output-format box)
static __device__ __forceinline__ void emit_item(uint32_t pos, uint32_t d, uint32_t idx,
    const float4* __restrict__ deltas, const float4* __restrict__ anchors,
    uint64_t* __restrict__ keyhi, uint32_t* __restrict__ keylo,
    float4* __restrict__ box4u) {
  float x1, y1, wc, hc; bool keep;
  compute_box(anchors[idx], deltas[idx], x1, y1, wc, hc, keep);
  float y2 = y1 + hc - 1.0f;                 // exactly as reference _nms
  keyhi[pos] = ((uint64_t)f2s(y2) << 32) | (uint32_t)(~d);
  keylo[pos] = ~idx;
  box4u[pos] = make_float4(x1, y1, wc, hc);
}

// ---------- K1: decode once, write d[], LDS hist over r8 -> per-XCD copy ----------
__global__ __launch_bounds__(256) void k_hA(const float* __restrict__ scores,
                                            const float4* __restrict__ deltas,
                                            const float4* __restrict__ anchors,
                                            uint32_t* __restrict__ darr,
                                            uint32_t* __restrict__ hist1r,
                                            uint32_t* __restrict__ zctr) {
  __shared__ uint32_t lh[320];
  int t = threadIdx.x;
  for (int j = t; j < 320; j += 256) lh[j] = 0;
  __syncthreads();
  int base = blockIdx.x * 256 + t;
  #pragma unroll
  for (int it = 0; it < 4; ++it) {
    int i = base + it * NQ;
    float x1, y1, wc, hc; bool keep;
    compute_box(anchors[i], deltas[i], x1, y1, wc, hc, keep);
    float s = scores[i];
    uint32_t d = keep ? score_key(s) : 0xFF800000u;
    darr[i] = d;
    uint32_t r8 = keep ? (255u - (kb18_of(s) >> 10)) : 256u;
    atomicAdd(&lh[r8], 1u);
  }
  __syncthreads();
  uint32_t* hdst = hist1r + (blockIdx.x & (NREP - 1)) * 320;  // XCD-local copy
  for (int j = t; j < 320; j += 256) {
    uint32_t c = lh[j];
    if (c) atomicAdd(&hdst[j], c);
  }
  if (blockIdx.x == 0) for (int j = t; j < 320; j += 256) zctr[j] = 0;  // ctr+valid
}

// ---------- K2: gather, two-phase (LDS staging, one global atomic per category) ----------
__global__ __launch_bounds__(256) void k_gather(const uint4* __restrict__ dv,
                                                const uint32_t* __restrict__ hist1r,
                                                uint32_t* __restrict__ ctr,
                                                uint64_t* __restrict__ Lb,
                                                uint64_t* __restrict__ keyhi,
                                                uint32_t* __restrict__ keylo,
                                                float4* __restrict__ box4u,
                                                const float4* __restrict__ deltas,
                                                const float4* __restrict__ anchors) {
  __shared__ uint64_t stA[1024];
  __shared__ uint64_t stB[1024];
  __shared__ uint32_t nA, nB, baseA, baseB, s_sel8;
  int t = threadIdx.x;
  if (t < 64) {
    uint32_t sel8, base1;
    pick1_f(hist1r, sel8, base1);
    if (t == 0) { s_sel8 = sel8; nA = 0; nB = 0; }
  }
  __syncthreads();
  uint32_t selR8 = s_sel8;

  int g = blockIdx.x * 256 + t;
  uint4 v = dv[g];
  uint32_t arr[4] = {v.x, v.y, v.z, v.w};
  #pragma unroll
  for (int k = 0; k < 4; ++k) {
    uint32_t d = arr[k];
    uint32_t idx = (uint32_t)(g * 4 + k);
    uint32_t r8 = (d <= 0x7FFFFFFFu)
                ? (255u - (kb18_of(__uint_as_float(0x7FFFFFFFu - d)) >> 10)) : 256u;
    if (r8 < selR8) {
      uint32_t p = atomicAdd(&nA, 1u);         // LDS atomic
      stA[p] = ((uint64_t)d << 32) | idx;
    } else if (r8 == selR8) {
      uint32_t q = atomicAdd(&nB, 1u);         // LDS atomic
      stB[q] = ((uint64_t)d << 32) | idx;
    }
  }
  __syncthreads();
  if (t == 0) {
    baseA = nA ? atomicAdd(&ctr[0], nA)  : 0u;
    baseB = nB ? atomicAdd(&ctr[32], nB) : 0u;   // separate cache line
  }
  __syncthreads();
  uint32_t mA = nA, mB = nB, bA = baseA, bB = baseB;
  for (uint32_t j = t; j < mA; j += 256) {
    uint64_t kj = stA[j];
    uint32_t p = bA + j;
    if (p < PRE_NMS_)
      emit_item(p, (uint32_t)(kj >> 32), (uint32_t)kj, deltas, anchors,
                keyhi, keylo, box4u);
  }
  for (uint32_t j = t; j < mB; j += 256) {
    uint32_t q = bB + j;
    if (q < LB_CAP) Lb[q] = stB[j];
  }
}

// ---------- K3: finish selection (1 block): level-2 histogram over Lb ----------
__global__ __launch_bounds__(256) void k_finish(const uint32_t* __restrict__ ctr,
                                                const uint64_t* __restrict__ Lb,
                                                uint64_t* __restrict__ keyhi,
                                                uint32_t* __restrict__ keylo,
                                                float4* __restrict__ box4u,
                                                const float4* __restrict__ deltas,
                                                const float4* __restrict__ anchors) {
  __shared__ uint32_t lh2[1024];
  __shared__ uint64_t bnd[256];
  __shared__ uint32_t bcnt, lcnt, s_sel10, s_base;
  int t = threadIdx.x;
  for (int j = t; j < 1024; j += 256) lh2[j] = 0;
  if (t == 0) { bcnt = 0; lcnt = 0; }
  __syncthreads();

  uint32_t C1 = ctr[0]; if (C1 > PRE_NMS_) C1 = PRE_NMS_;
  uint32_t Cb = ctr[32]; if (Cb > LB_CAP) Cb = LB_CAP;
  uint32_t T = PRE_NMS_ - C1;

  for (uint32_t j = t; j < Cb; j += 256) {
    uint32_t d = (uint32_t)(Lb[j] >> 32);
    uint32_t r10 = (d <= 0x7FFFFFFFu)
                 ? (1023u - (kb18_of(__uint_as_float(0x7FFFFFFFu - d)) & 1023u)) : 0u;
    atomicAdd(&lh2[r10], 1u);
  }
  __syncthreads();
  if (t < 64) {
    uint32_t sel10 = 0xFFFFFFFFu, b2 = 0;
    if (T > 0) pickT_lds(lh2, T, sel10, b2);
    if (t == 0) { s_sel10 = sel10; s_base = b2; }
  }
  __syncthreads();
  uint32_t sel10 = s_sel10, C2base = s_base;

  for (uint32_t j = t; j < Cb; j += 256) {
    uint64_t kj = Lb[j];
    uint32_t d = (uint32_t)(kj >> 32), idx = (uint32_t)kj;
    uint32_t r10 = (d <= 0x7FFFFFFFu)
                 ? (1023u - (kb18_of(__uint_as_float(0x7FFFFFFFu - d)) & 1023u)) : 0u;
    if (r10 < sel10) {
      uint32_t p = C1 + atomicAdd(&lcnt, 1u);
      if (p < PRE_NMS_) emit_item(p, d, idx, deltas, anchors, keyhi, keylo, box4u);
    } else if (r10 == sel10) {
      uint32_t q = atomicAdd(&bcnt, 1u);
      if (q < 256) bnd[q] = kj;
    }
  }
  __syncthreads();
  uint32_t B = (bcnt < 256u) ? bcnt : 256u;
  uint32_t T2 = (T > C2base) ? (T - C2base) : 0u;
  for (uint32_t j = t; j < B; j += 256) {
    uint64_t kj = bnd[j];
    uint32_t r = 0;
    for (uint32_t k = 0; k < B; ++k) r += (bnd[k] < kj) ? 1u : 0u;
    if (r < T2)
      emit_item(C1 + C2base + r, (uint32_t)(kj >> 32), (uint32_t)kj,
                deltas, anchors, keyhi, keylo, box4u);
  }
  // sentinel padding
  for (int j = PRE_NMS_ + t; j < NPAD; j += 256) {
    keyhi[j] = 0;
    keylo[j] = (uint32_t)(NPAD - j);
    box4u[j] = make_float4(0.f, 0.f, 0.f, 0.f);
  }
}

// ---------- K4: pairwise rank, chunked; plain stores rank2d[i][16] ----------
__global__ __launch_bounds__(512) void k_rank(const uint64_t* __restrict__ keyhi,
                                              const uint32_t* __restrict__ keylo,
                                              uint32_t* __restrict__ rank2d) {
  __shared__ uint64_t shi[768];
  __shared__ uint32_t slo[768];
  int t = threadIdx.x;
  int ib = blockIdx.x >> 3, c = blockIdx.x & 7, base = c * 768;
  for (int j = t; j < 768; j += 512) { shi[j] = keyhi[base + j]; slo[j] = keylo[base + j]; }
  __syncthreads();
  int i = ib * 256 + (t >> 1);
  int h = t & 1;
  uint64_t hi = keyhi[i]; uint32_t lo = keylo[i];
  uint32_t cnt = 0;
  int j0 = h * 384;
  for (int j = j0; j < j0 + 384; ++j) {
    uint64_t hj = shi[j]; uint32_t lj = slo[j];
    cnt += ((hj > hi) || (hj == hi && lj > lo)) ? 1u : 0u;
  }
  rank2d[i * 16 + c * 2 + h] = cnt;
}

// ---------- K5: scatter+mat fused ----------
__global__ __launch_bounds__(512) void k_matsc(const uint64_t* __restrict__ keyhi,
                                               const uint32_t* __restrict__ rank2d,
                                               const float4* __restrict__ box4u,
                                               float4* __restrict__ sobox,
                                               unsigned long long* __restrict__ valid,
                                               uint64_t* __restrict__ M) {
  __shared__ float4 sb[NPAD];
  __shared__ float  sa[NPAD];
  int t = threadIdx.x;
  int b = blockIdx.x;
  for (int i = t; i < NPAD; i += 512) {
    const uint4* rp = (const uint4*)(rank2d + (size_t)i * 16);
    uint4 r0 = rp[0], r1 = rp[1], r2 = rp[2], r3 = rp[3];
    uint32_t r = r0.x+r0.y+r0.z+r0.w + r1.x+r1.y+r1.z+r1.w
               + r2.x+r2.y+r2.z+r2.w + r3.x+r3.y+r3.z+r3.w;
    float4 bx = box4u[i];
    float x2 = bx.x + bx.z - 1.0f;              // exactly as reference _nms
    float y2 = bx.y + bx.w - 1.0f;
    sb[r] = make_float4(bx.x, bx.y, x2, y2);
    sa[r] = bx.z * bx.w;
    if (b == 0) {
      sobox[r] = bx;
      uint32_t d = ~(uint32_t)(keyhi[i] & 0xFFFFFFFFu);
      if (d < 0xFF800000u)                      // finite masked score only
        atomicOr(&valid[r >> 6], 1ull << (r & 63));
    }
  }
  __syncthreads();
  int wid = t >> 6, l = t & 63;
  #pragma unroll
  for (int rr = 0; rr < 4; ++rr) {
    int r = b * 32 + wid * 4 + rr;
    float4 rb = sb[r];
    for (int w = 0; w < NWORD; ++w) {
      int j = w * 64 + l;
      float4 cb = sb[j];
      float ca = sa[j];
      float xx1 = fmaxf(cb.x, rb.x), yy1 = fmaxf(cb.y, rb.y);
      float xx2 = fminf(cb.z, rb.z), yy2 = fminf(cb.w, rb.w);
      float iw = fmaxf(xx2 - xx1 + 1.0f, 0.0f);
      float ih = fmaxf(yy2 - yy1 + 1.0f, 0.0f);
      float ratio = (iw * ih) / ca;             // IEEE divide, exact semantics
      unsigned long long mm = __ballot(!(ratio < 0.7f));
      if (l == 0) M[(size_t)r * NWORD + w] = mm;
    }
  }
}

// ---------- K6: batched-greedy NMS (R6 structure, SROW shfls -> col gathers) ----------
#define FOR16(F) F(0) F(1) F(2) F(3) F(4) F(5) F(6) F(7) \
                 F(8) F(9) F(10) F(11) F(12) F(13) F(14) F(15)

__global__ __launch_bounds__(64) void k_seq(const unsigned long long* __restrict__ valid,
                                            const uint64_t* __restrict__ M,
                                            const float4* __restrict__ sobox,
                                            float* __restrict__ out) {
  __shared__ int cslot[KB];
  int l = threadIdx.x;
  unsigned long long v0 = valid[l];
  unsigned long long v1 = (l < 32) ? valid[64 + l] : 0ull;
  uint32_t cnt = 0;

  for (;;) {
    if (cnt >= POST_NMS_) break;
    // ---- rank valid candidates (scan words 0-63; 64-95 only if needed) ----
    uint32_t n0 = (uint32_t)__popcll(v0);
    uint32_t inc0 = wscan(n0, l);
    uint32_t T0 = __shfl(inc0, 63);
    uint32_t ex0 = inc0 - n0;
    uint32_t m, ex1 = KB;
    if (T0 < KB) {
      uint32_t n1 = (uint32_t)__popcll(v1);
      uint32_t inc1 = wscan(n1, l);
      uint32_t T1 = __shfl(inc1, 63);
      uint32_t TV = T0 + T1;
      if (TV == 0) break;
      m = (TV < KB) ? TV : KB;
      ex1 = T0 + inc1 - n1;
    } else {
      m = KB;
    }

    // ---- owners write candidate ids to LDS table by rank (single wave) ----
    if (l < KB) cslot[l] = 0;
    __builtin_amdgcn_sched_barrier(0);
    if (ex0 < KB) {
      unsigned long long w = v0; uint32_t r = ex0;
      while (w && r < KB) { int b = __ffsll(w) - 1; cslot[r] = l * 64 + b; ++r; w &= w - 1; }
    }
    if (ex1 < KB && v1) {
      unsigned long long w = v1; uint32_t r = ex1;
      while (w && r < KB) { int b = __ffsll(w) - 1; cslot[r] = (64 + l) * 64 + b; ++r; w &= w - 1; }
    }
    __builtin_amdgcn_sched_barrier(0);

    // ---- uniform broadcast reads of the table + own-column id ----
#define CUDECL(k) int cu_##k = cslot[k];
    FOR16(CUDECL)
#undef CUDECL
    int c_own = cslot[(l < KB) ? l : 0];
    uint32_t ow = (uint32_t)c_own >> 6, ob = (uint32_t)c_own & 63;

    // ---- ONE latency window: rows + column words + own box ----
#define ROWDECL(k) uint64_t rm0_##k = 0, rm1_##k = 0;
    FOR16(ROWDECL)
#undef ROWDECL
#define ROWLOAD(k) if (k < (int)m) { const uint64_t* p = M + (size_t)cu_##k * NWORD; \
                     rm0_##k = p[l]; rm1_##k = (l < 32) ? p[64 + l] : 0ull; }
    FOR16(ROWLOAD)
#undef ROWLOAD
    uint32_t col = 0;
#define COLLOAD(k) if (k < (int)m) { \
                     uint64_t wq = M[(size_t)cu_##k * NWORD + ow]; \
                     col |= (uint32_t)((wq >> ob) & 1ull) << k; }
    FOR16(COLLOAD)
#undef COLLOAD
    float4 obox = make_float4(0.f, 0.f, 0.f, 0.f);
    if (l < KB) obox = sobox[c_own];

    // ---- ballot-greedy: one ballot per candidate (no shfl chain) ----
    uint32_t cnt0 = cnt;
    uint32_t wm = 0;
#define GREEDY(k) { \
      unsigned long long bal = __ballot((l == k) && ((col & wm) == 0u)); \
      if ((k < (int)m) && (cnt < POST_NMS_) && ((bal >> k) & 1ull)) { \
        wm |= 1u << k; ++cnt; } }
    FOR16(GREEDY)
#undef GREEDY

    // ---- write winner boxes in order ----
    if (l < KB && ((wm >> l) & 1)) {
      uint32_t pos = cnt0 + (uint32_t)__popc(wm & ((1u << l) - 1));
      *(float4*)(out + (size_t)pos * 4) = obox;
    }

    // ---- combined suppression from held winner rows (no re-load) ----
    uint64_t comb0 = 0, comb1 = 0;
#define COMB(k) if ((wm >> k) & 1) { comb0 |= rm0_##k; comb1 |= rm1_##k; }
    FOR16(COMB)
#undef COMB
    v0 &= ~comb0; v1 &= ~comb1;
  }

  // zero-fill remaining output rows
  for (int j = l; j < (int)(POST_NMS_ - cnt) * 4; j += 64) out[cnt * 4 + j] = 0.0f;
}

// ---------- launch ----------
extern "C" void kernel_launch(void* const* d_in, const int* in_sizes, int n_in,
                              void* d_out, int out_size, void* d_ws, size_t ws_size,
                              hipStream_t stream) {
  const float*  scores  = (const float*)d_in[0];
  const float4* deltas  = (const float4*)d_in[1];
  const float4* anchors = (const float4*)d_in[2];
  float* out = (float*)d_out;

  uint8_t* w8 = (uint8_t*)d_ws;
  uint32_t* darr  = (uint32_t*)w8;
  uint64_t* M     = (uint64_t*)w8;                          // 4,718,592
  float4*   sobox = (float4*)(w8 + 4841472);                //  98,304 -> 4,939,776
  uint64_t* keyhi  = (uint64_t*)(w8 + 5308416);             //  49,152
  uint32_t* keylo  = (uint32_t*)(w8 + 5357568);             //  24,576
  float4*   box4u  = (float4*)  (w8 + 5382144);             //  98,304
  uint32_t* rank2d = (uint32_t*)(w8 + 5480448);             // 393,216 -> 5,873,664
  uint32_t* hist1r = (uint32_t*)(w8 + 5873664);             //  10,240
  uint32_t* ctr    = (uint32_t*)(w8 + 5883904);             //     256
  unsigned long long* valid = (unsigned long long*)(w8 + 5884160); // 1,024
  uint64_t* Lb     = (uint64_t*)(w8 + 5885184);             // 131,072 -> 6,016,256

  const uint4* dv = (const uint4*)darr;

  hipMemsetAsync(hist1r, 0, 10240, stream);

  k_hA    <<<NB, 256, 0, stream>>>(scores, deltas, anchors, darr, hist1r, ctr);
  k_gather<<<NB, 256, 0, stream>>>(dv, hist1r, ctr, Lb, keyhi, keylo, box4u,
                                   deltas, anchors);
  k_finish<<<1, 256, 0, stream>>>(ctr, Lb, keyhi, keylo, box4u, deltas, anchors);
  k_rank  <<<MATB, 512, 0, stream>>>(keyhi, keylo, rank2d);
  k_matsc <<<MATB, 512, 0, stream>>>(keyhi, rank2d, box4u, sobox, valid, M);
  k_seq   <<<1, 64, 0, stream>>>(valid, M, sobox, out);
}

// Round 21
// 254.960 us; speedup vs baseline: 1.0709x; 1.0709x over previous
//
#include <hip/hip_runtime.h>
#include <stdint.h>

#define NN 1327104
#define NQ 331776
#define NB 1296
#define PRE_NMS_ 6000
#define POST_NMS_ 300
#define LB_CAP 16384
#define NPAD 6144
#define NWORD 96
#define KB 16
#define MATB 192
#define NREP 8

// ---------- helpers ----------

static __device__ __forceinline__ uint32_t score_key(float s) {
  uint32_t b = __float_as_uint(s);
  uint32_t u = b ^ (((int32_t)b < 0) ? 0xFFFFFFFFu : 0x80000000u);
  return ~u;                     // ascending key == descending score
}

static __device__ __forceinline__ uint32_t f2s(float v) {
  uint32_t b = __float_as_uint(v);
  return b ^ (((int32_t)b < 0) ? 0xFFFFFFFFu : 0x80000000u);
}

// Exact replication of reference box decode + _clip_boxes + keep mask.
static __device__ __forceinline__ void compute_box(float4 an, float4 de,
    float& x1, float& y1, float& wc, float& hc, bool& keep) {
  float bx = fmaxf(an.x + de.x, 0.0f);
  float by = fmaxf(an.y + de.y, 0.0f);
  float bw = fmaxf(an.z + de.z, 0.0f);
  float bh = fmaxf(an.w + de.w, 0.0f);
  float x2 = bx + bw - 1.0f;
  float y2 = by + bh - 1.0f;
  x1 = fminf(bx, 383.0f);
  y1 = fminf(by, 383.0f);
  x2 = fminf(x2, 383.0f);
  y2 = fminf(y2, 383.0f);
  wc = x2 - x1 + 1.0f;
  hc = y2 - y1 + 1.0f;
  keep = (wc >= 2.0f) && (hc >= 2.0f);
}

// uniform 18-bit fixed-point bucket (x 2^18 exact for floats -> monotone)
static __device__ __forceinline__ uint32_t kb18_of(float s) {
  return (uint32_t)(s * 262144.0f);
}

static __device__ __forceinline__ uint32_t wscan(uint32_t v, int l) {
  #pragma unroll
  for (int off = 1; off < 64; off <<= 1) {
    uint32_t u = __shfl_up(v, off);
    if (l >= off) v += u;
  }
  return v;
}

// pick level 1 over replicated hist1r[NREP][320] (257 used): (selR8, base1)
static __device__ __forceinline__ void pick1_f(const uint32_t* __restrict__ h1r,
                                               uint32_t& selR8, uint32_t& base1) {
  int l = threadIdx.x & 63;
  uint32_t a0 = 0, a1 = 0, a2 = 0, a3 = 0, a4 = 0;
  #pragma unroll
  for (int r = 0; r < NREP; ++r) {
    const uint32_t* h1 = h1r + r * 320;
    a0 += h1[l*5]; a1 += h1[l*5+1]; a2 += h1[l*5+2]; a3 += h1[l*5+3]; a4 += h1[l*5+4];
  }
  uint32_t c0 = a0, c1 = c0+a1, c2 = c1+a2, c3 = c2+a3, c4 = c3+a4;
  uint32_t inc = wscan(c4, l);
  uint32_t excl = inc - c4;
  bool hit = (excl < PRE_NMS_) && (inc >= PRE_NMS_);
  unsigned long long hb = __ballot(hit);
  int hl = __ffsll(hb) - 1;
  uint32_t k, cb;
  if      (excl + c0 >= PRE_NMS_) { k = 0; cb = 0;  }
  else if (excl + c1 >= PRE_NMS_) { k = 1; cb = c0; }
  else if (excl + c2 >= PRE_NMS_) { k = 2; cb = c1; }
  else if (excl + c3 >= PRE_NMS_) { k = 3; cb = c2; }
  else                            { k = 4; cb = c3; }
  selR8 = __shfl(l*5u + k, hl);
  base1 = __shfl(excl + cb, hl);
}

// pick over LDS hist[1024] with target T>=1: (sel10, base)
static __device__ __forceinline__ void pickT_lds(const uint32_t* __restrict__ h2,
                                                 uint32_t T,
                                                 uint32_t& sel10, uint32_t& base) {
  int l = threadIdx.x & 63;
  uint32_t h[16];
  #pragma unroll
  for (int k = 0; k < 16; ++k) h[k] = h2[l*16 + k];
  uint32_t cum[16]; cum[0] = h[0];
  #pragma unroll
  for (int k = 1; k < 16; ++k) cum[k] = cum[k-1] + h[k];
  uint32_t inc = wscan(cum[15], l);
  uint32_t excl = inc - cum[15];
  bool hit = (excl < T) && (inc >= T);
  unsigned long long hb = __ballot(hit);
  int hl = __ffsll(hb) - 1;
  uint32_t k = 15, cb = cum[14];
  #pragma unroll
  for (int kk = 15; kk >= 0; --kk)
    if (excl + cum[kk] >= T) { k = (uint32_t)kk; cb = kk ? cum[kk-1] : 0u; }
  sel10 = __shfl(l*16u + k, hl);
  base  = __shfl(excl + cb, hl);
}

// decode + write one selection entry (NMS key + output-format box)
static __device__ __forceinline__ void emit_item(uint32_t pos, uint32_t d, uint32_t idx,
    const float4* __restrict__ deltas, const float4* __restrict__ anchors,
    uint64_t* __restrict__ keyhi, uint32_t* __restrict__ keylo,
    float4* __restrict__ box4u) {
  float x1, y1, wc, hc; bool keep;
  compute_box(anchors[idx], deltas[idx], x1, y1, wc, hc, keep);
  float y2 = y1 + hc - 1.0f;                 // exactly as reference _nms
  keyhi[pos] = ((uint64_t)f2s(y2) << 32) | (uint32_t)(~d);
  keylo[pos] = ~idx;
  box4u[pos] = make_float4(x1, y1, wc, hc);
}

// ---------- K1: decode once, write d[], LDS hist over r8 -> per-XCD copy ----------
__global__ __launch_bounds__(256) void k_hA(const float* __restrict__ scores,
                                            const float4* __restrict__ deltas,
                                            const float4* __restrict__ anchors,
                                            uint32_t* __restrict__ darr,
                                            uint32_t* __restrict__ hist1r,
                                            uint32_t* __restrict__ zctr) {
  __shared__ uint32_t lh[320];
  int t = threadIdx.x;
  for (int j = t; j < 320; j += 256) lh[j] = 0;
  __syncthreads();
  int base = blockIdx.x * 256 + t;
  #pragma unroll
  for (int it = 0; it < 4; ++it) {
    int i = base + it * NQ;
    float x1, y1, wc, hc; bool keep;
    compute_box(anchors[i], deltas[i], x1, y1, wc, hc, keep);
    float s = scores[i];
    uint32_t d = keep ? score_key(s) : 0xFF800000u;
    darr[i] = d;
    uint32_t r8 = keep ? (255u - (kb18_of(s) >> 10)) : 256u;
    atomicAdd(&lh[r8], 1u);
  }
  __syncthreads();
  uint32_t* hdst = hist1r + (blockIdx.x & (NREP - 1)) * 320;  // XCD-local copy
  for (int j = t; j < 320; j += 256) {
    uint32_t c = lh[j];
    if (c) atomicAdd(&hdst[j], c);
  }
  if (blockIdx.x == 0) for (int j = t; j < 320; j += 256) zctr[j] = 0;  // ctr+valid
}

// ---------- K2: gather, two-phase (LDS staging, one global atomic per category) ----------
__global__ __launch_bounds__(256) void k_gather(const uint4* __restrict__ dv,
                                                const uint32_t* __restrict__ hist1r,
                                                uint32_t* __restrict__ ctr,
                                                uint64_t* __restrict__ Lb,
                                                uint64_t* __restrict__ keyhi,
                                                uint32_t* __restrict__ keylo,
                                                float4* __restrict__ box4u,
                                                const float4* __restrict__ deltas,
                                                const float4* __restrict__ anchors) {
  __shared__ uint64_t stA[1024];
  __shared__ uint64_t stB[1024];
  __shared__ uint32_t nA, nB, baseA, baseB, s_sel8;
  int t = threadIdx.x;
  if (t < 64) {
    uint32_t sel8, base1;
    pick1_f(hist1r, sel8, base1);
    if (t == 0) { s_sel8 = sel8; nA = 0; nB = 0; }
  }
  __syncthreads();
  uint32_t selR8 = s_sel8;

  int g = blockIdx.x * 256 + t;
  uint4 v = dv[g];
  uint32_t arr[4] = {v.x, v.y, v.z, v.w};
  #pragma unroll
  for (int k = 0; k < 4; ++k) {
    uint32_t d = arr[k];
    uint32_t idx = (uint32_t)(g * 4 + k);
    uint32_t r8 = (d <= 0x7FFFFFFFu)
                ? (255u - (kb18_of(__uint_as_float(0x7FFFFFFFu - d)) >> 10)) : 256u;
    if (r8 < selR8) {
      uint32_t p = atomicAdd(&nA, 1u);         // LDS atomic
      stA[p] = ((uint64_t)d << 32) | idx;
    } else if (r8 == selR8) {
      uint32_t q = atomicAdd(&nB, 1u);         // LDS atomic
      stB[q] = ((uint64_t)d << 32) | idx;
    }
  }
  __syncthreads();
  if (t == 0) {
    baseA = nA ? atomicAdd(&ctr[0], nA)  : 0u;
    baseB = nB ? atomicAdd(&ctr[32], nB) : 0u;   // separate cache line
  }
  __syncthreads();
  uint32_t mA = nA, mB = nB, bA = baseA, bB = baseB;
  for (uint32_t j = t; j < mA; j += 256) {
    uint64_t kj = stA[j];
    uint32_t p = bA + j;
    if (p < PRE_NMS_)
      emit_item(p, (uint32_t)(kj >> 32), (uint32_t)kj, deltas, anchors,
                keyhi, keylo, box4u);
  }
  for (uint32_t j = t; j < mB; j += 256) {
    uint32_t q = bB + j;
    if (q < LB_CAP) Lb[q] = stB[j];
  }
}

// ---------- K3: finish selection (1 block): level-2 histogram over Lb ----------
__global__ __launch_bounds__(256) void k_finish(const uint32_t* __restrict__ ctr,
                                                const uint64_t* __restrict__ Lb,
                                                uint64_t* __restrict__ keyhi,
                                                uint32_t* __restrict__ keylo,
                                                float4* __restrict__ box4u,
                                                const float4* __restrict__ deltas,
                                                const float4* __restrict__ anchors) {
  __shared__ uint32_t lh2[1024];
  __shared__ uint64_t bnd[256];
  __shared__ uint32_t bcnt, lcnt, s_sel10, s_base;
  int t = threadIdx.x;
  for (int j = t; j < 1024; j += 256) lh2[j] = 0;
  if (t == 0) { bcnt = 0; lcnt = 0; }
  __syncthreads();

  uint32_t C1 = ctr[0]; if (C1 > PRE_NMS_) C1 = PRE_NMS_;
  uint32_t Cb = ctr[32]; if (Cb > LB_CAP) Cb = LB_CAP;
  uint32_t T = PRE_NMS_ - C1;

  for (uint32_t j = t; j < Cb; j += 256) {
    uint32_t d = (uint32_t)(Lb[j] >> 32);
    uint32_t r10 = (d <= 0x7FFFFFFFu)
                 ? (1023u - (kb18_of(__uint_as_float(0x7FFFFFFFu - d)) & 1023u)) : 0u;
    atomicAdd(&lh2[r10], 1u);
  }
  __syncthreads();
  if (t < 64) {
    uint32_t sel10 = 0xFFFFFFFFu, b2 = 0;
    if (T > 0) pickT_lds(lh2, T, sel10, b2);
    if (t == 0) { s_sel10 = sel10; s_base = b2; }
  }
  __syncthreads();
  uint32_t sel10 = s_sel10, C2base = s_base;

  for (uint32_t j = t; j < Cb; j += 256) {
    uint64_t kj = Lb[j];
    uint32_t d = (uint32_t)(kj >> 32), idx = (uint32_t)kj;
    uint32_t r10 = (d <= 0x7FFFFFFFu)
                 ? (1023u - (kb18_of(__uint_as_float(0x7FFFFFFFu - d)) & 1023u)) : 0u;
    if (r10 < sel10) {
      uint32_t p = C1 + atomicAdd(&lcnt, 1u);
      if (p < PRE_NMS_) emit_item(p, d, idx, deltas, anchors, keyhi, keylo, box4u);
    } else if (r10 == sel10) {
      uint32_t q = atomicAdd(&bcnt, 1u);
      if (q < 256) bnd[q] = kj;
    }
  }
  __syncthreads();
  uint32_t B = (bcnt < 256u) ? bcnt : 256u;
  uint32_t T2 = (T > C2base) ? (T - C2base) : 0u;
  for (uint32_t j = t; j < B; j += 256) {
    uint64_t kj = bnd[j];
    uint32_t r = 0;
    for (uint32_t k = 0; k < B; ++k) r += (bnd[k] < kj) ? 1u : 0u;
    if (r < T2)
      emit_item(C1 + C2base + r, (uint32_t)(kj >> 32), (uint32_t)kj,
                deltas, anchors, keyhi, keylo, box4u);
  }
  // sentinel padding
  for (int j = PRE_NMS_ + t; j < NPAD; j += 256) {
    keyhi[j] = 0;
    keylo[j] = (uint32_t)(NPAD - j);
    box4u[j] = make_float4(0.f, 0.f, 0.f, 0.f);
  }
}

// ---------- K4: pairwise rank, chunked; plain stores rank2d[i][16] ----------
__global__ __launch_bounds__(512) void k_rank(const uint64_t* __restrict__ keyhi,
                                              const uint32_t* __restrict__ keylo,
                                              uint32_t* __restrict__ rank2d) {
  __shared__ uint64_t shi[768];
  __shared__ uint32_t slo[768];
  int t = threadIdx.x;
  int ib = blockIdx.x >> 3, c = blockIdx.x & 7, base = c * 768;
  for (int j = t; j < 768; j += 512) { shi[j] = keyhi[base + j]; slo[j] = keylo[base + j]; }
  __syncthreads();
  int i = ib * 256 + (t >> 1);
  int h = t & 1;
  uint64_t hi = keyhi[i]; uint32_t lo = keylo[i];
  uint32_t cnt = 0;
  int j0 = h * 384;
  for (int j = j0; j < j0 + 384; ++j) {
    uint64_t hj = shi[j]; uint32_t lj = slo[j];
    cnt += ((hj > hi) || (hj == hi && lj > lo)) ? 1u : 0u;
  }
  rank2d[i * 16 + c * 2 + h] = cnt;
}

// ---------- K5: scatter+mat fused ----------
__global__ __launch_bounds__(512) void k_matsc(const uint64_t* __restrict__ keyhi,
                                               const uint32_t* __restrict__ rank2d,
                                               const float4* __restrict__ box4u,
                                               float4* __restrict__ sobox,
                                               unsigned long long* __restrict__ valid,
                                               uint64_t* __restrict__ M) {
  __shared__ float4 sb[NPAD];
  __shared__ float  sa[NPAD];
  int t = threadIdx.x;
  int b = blockIdx.x;
  for (int i = t; i < NPAD; i += 512) {
    const uint4* rp = (const uint4*)(rank2d + (size_t)i * 16);
    uint4 r0 = rp[0], r1 = rp[1], r2 = rp[2], r3 = rp[3];
    uint32_t r = r0.x+r0.y+r0.z+r0.w + r1.x+r1.y+r1.z+r1.w
               + r2.x+r2.y+r2.z+r2.w + r3.x+r3.y+r3.z+r3.w;
    float4 bx = box4u[i];
    float x2 = bx.x + bx.z - 1.0f;              // exactly as reference _nms
    float y2 = bx.y + bx.w - 1.0f;
    sb[r] = make_float4(bx.x, bx.y, x2, y2);
    sa[r] = bx.z * bx.w;
    if (b == 0) {
      sobox[r] = bx;
      uint32_t d = ~(uint32_t)(keyhi[i] & 0xFFFFFFFFu);
      if (d < 0xFF800000u)                      // finite masked score only
        atomicOr(&valid[r >> 6], 1ull << (r & 63));
    }
  }
  __syncthreads();
  int wid = t >> 6, l = t & 63;
  #pragma unroll
  for (int rr = 0; rr < 4; ++rr) {
    int r = b * 32 + wid * 4 + rr;
    float4 rb = sb[r];
    for (int w = 0; w < NWORD; ++w) {
      int j = w * 64 + l;
      float4 cb = sb[j];
      float ca = sa[j];
      float xx1 = fmaxf(cb.x, rb.x), yy1 = fmaxf(cb.y, rb.y);
      float xx2 = fminf(cb.z, rb.z), yy2 = fminf(cb.w, rb.w);
      float iw = fmaxf(xx2 - xx1 + 1.0f, 0.0f);
      float ih = fmaxf(yy2 - yy1 + 1.0f, 0.0f);
      float ratio = (iw * ih) / ca;             // IEEE divide, exact semantics
      unsigned long long mm = __ballot(!(ratio < 0.7f));
      if (l == 0) M[(size_t)r * NWORD + w] = mm;
    }
  }
}

// ---------- K6: batched-greedy NMS (proven 80µs structure: KB=16, 1 wave) ----------
#define FOR16(F) F(0) F(1) F(2) F(3) F(4) F(5) F(6) F(7) \
                 F(8) F(9) F(10) F(11) F(12) F(13) F(14) F(15)

__global__ __launch_bounds__(64) void k_seq(const unsigned long long* __restrict__ valid,
                                            const uint64_t* __restrict__ M,
                                            const float4* __restrict__ sobox,
                                            float* __restrict__ out) {
  __shared__ int cslot[KB];
  int l = threadIdx.x;
  unsigned long long v0 = valid[l];
  unsigned long long v1 = (l < 32) ? valid[64 + l] : 0ull;
  uint32_t cnt = 0;

  for (;;) {
    // ---- count + prefix-rank valid candidates in word order ----
    uint32_t n0 = (uint32_t)__popcll(v0);
    uint32_t inc0 = wscan(n0, l);
    uint32_t T0 = __shfl(inc0, 63);
    uint32_t ex0 = inc0 - n0;
    uint32_t n1 = (uint32_t)__popcll(v1);
    uint32_t inc1 = wscan(n1, l);
    uint32_t T1 = __shfl(inc1, 63);
    uint32_t ex1 = T0 + inc1 - n1;
    uint32_t TV = T0 + T1;
    if (cnt >= POST_NMS_ || TV == 0) break;
    uint32_t m = (TV < KB) ? TV : KB;

    // ---- extract first m valid candidate indices into cslot ----
    __syncthreads();
    if (l < KB) cslot[l] = 0;
    __syncthreads();
    if (ex0 < KB) {
      unsigned long long w = v0; uint32_t r = ex0;
      while (w && r < KB) { int b = __ffsll(w) - 1; cslot[r] = l * 64 + b; ++r; w &= w - 1; }
    }
    if (ex1 < KB && v1) {
      unsigned long long w = v1; uint32_t r = ex1;
      while (w && r < KB) { int b = __ffsll(w) - 1; cslot[r] = (64 + l) * 64 + b; ++r; w &= w - 1; }
    }
    __syncthreads();

    // ---- parallel row loads for the m candidates ----
#define ROWDECL(k) uint64_t rm0_##k = 0, rm1_##k = 0;
    FOR16(ROWDECL)
#undef ROWDECL
#define ROWLOAD(k) if (k < (int)m) { const uint64_t* p = M + (size_t)cslot[k] * NWORD; \
                     rm0_##k = p[l]; rm1_##k = (l < 32) ? p[64 + l] : 0ull; }
    FOR16(ROWLOAD)
#undef ROWLOAD
    // box prefetch: lane k holds candidate k's output box
    float4 obox = make_float4(0.f, 0.f, 0.f, 0.f);
    if (l < KB) obox = sobox[cslot[l]];

    // ---- build S[k][j] = M[ck][cj] as uniform 16-bit rows via shfl+ballot ----
    uint32_t cj = (l < KB) ? (uint32_t)cslot[l] : 0u;
    uint32_t wj = cj >> 6, bj = cj & 63;
    int srcA = (int)(wj & 63), srcB = (int)(wj & 31);
    uint32_t srow[KB];
#define SROW(k) { uint64_t a = __shfl((unsigned long long)rm0_##k, srcA); \
                  uint64_t b = __shfl((unsigned long long)rm1_##k, srcB); \
                  uint64_t sel = (wj < 64) ? a : b; \
                  uint32_t bit = (l < KB && k < (int)m) ? (uint32_t)((sel >> bj) & 1) : 0u; \
                  srow[k] = (uint32_t)(__ballot(bit) & 0xFFFFull); }
    FOR16(SROW)
#undef SROW

    // ---- exact greedy resolve over the m candidates (uniform scalar) ----
    uint32_t cnt0 = cnt;
    uint32_t wm = 0, supp = 0;
    #pragma unroll
    for (int k = 0; k < KB; ++k) {
      if (k < (int)m && cnt < POST_NMS_ && !((supp >> k) & 1)) {
        wm |= 1u << k; ++cnt; supp |= srow[k];
      }
    }

    // ---- write winner boxes in order ----
    if (l < KB && ((wm >> l) & 1)) {
      uint32_t pos = cnt0 + (uint32_t)__popc(wm & ((1u << l) - 1));
      *(float4*)(out + (size_t)pos * 4) = obox;
    }

    // ---- apply combined suppression ----
    uint64_t comb0 = 0, comb1 = 0;
#define COMB(k) if ((wm >> k) & 1) { comb0 |= rm0_##k; comb1 |= rm1_##k; }
    FOR16(COMB)
#undef COMB
    v0 &= ~comb0; v1 &= ~comb1;
  }

  // zero-fill remaining output rows
  for (int j = l; j < (int)(POST_NMS_ - cnt) * 4; j += 64) out[cnt * 4 + j] = 0.0f;
}

// ---------- launch ----------
extern "C" void kernel_launch(void* const* d_in, const int* in_sizes, int n_in,
                              void* d_out, int out_size, void* d_ws, size_t ws_size,
                              hipStream_t stream) {
  const float*  scores  = (const float*)d_in[0];
  const float4* deltas  = (const float4*)d_in[1];
  const float4* anchors = (const float4*)d_in[2];
  float* out = (float*)d_out;

  uint8_t* w8 = (uint8_t*)d_ws;
  uint32_t* darr  = (uint32_t*)w8;
  uint64_t* M     = (uint64_t*)w8;                          // 4,718,592
  float4*   sobox = (float4*)(w8 + 4841472);                //  98,304 -> 4,939,776
  uint64_t* keyhi  = (uint64_t*)(w8 + 5308416);             //  49,152
  uint32_t* keylo  = (uint32_t*)(w8 + 5357568);             //  24,576
  float4*   box4u  = (float4*)  (w8 + 5382144);             //  98,304
  uint32_t* rank2d = (uint32_t*)(w8 + 5480448);             // 393,216 -> 5,873,664
  uint32_t* hist1r = (uint32_t*)(w8 + 5873664);             //  10,240
  uint32_t* ctr    = (uint32_t*)(w8 + 5883904);             //     256
  unsigned long long* valid = (unsigned long long*)(w8 + 5884160); // 1,024
  uint64_t* Lb     = (uint64_t*)(w8 + 5885184);             // 131,072 -> 6,016,256

  const uint4* dv = (const uint4*)darr;

  hipMemsetAsync(hist1r, 0, 10240, stream);

  k_hA    <<<NB, 256, 0, stream>>>(scores, deltas, anchors, darr, hist1r, ctr);
  k_gather<<<NB, 256, 0, stream>>>(dv, hist1r, ctr, Lb, keyhi, keylo, box4u,
                                   deltas, anchors);
  k_finish<<<1, 256, 0, stream>>>(ctr, Lb, keyhi, keylo, box4u, deltas, anchors);
  k_rank  <<<MATB, 512, 0, stream>>>(keyhi, keylo, rank2d);
  k_matsc <<<MATB, 512, 0, stream>>>(keyhi, rank2d, box4u, sobox, valid, M);
  k_seq   <<<1, 64, 0, stream>>>(valid, M, sobox, out);
}